// Round 8
// baseline (87.713 us; speedup 1.0000x reference)
//
#include <hip/hip_runtime.h>
#include <math.h>

#define NQ 12
#define DIM 4096
#define NLAYER 4
#define NT 256

typedef float v2 __attribute__((ext_vector_type(2)));

__device__ __forceinline__ v2 mkv2(float a, float b) { v2 r; r.x = a; r.y = b; return r; }
__device__ __forceinline__ v2 sp(float a) { v2 r; r.x = a; r.y = a; return r; }
__device__ __forceinline__ v2 pkfma(v2 a, float b, v2 c) {
  return __builtin_elementwise_fma(a, sp(b), c);
}

// CNOT-cascade gather map (verified R1-R7): post-perm label y sits at sfun(y).
constexpr int sfun_c(int z) {
  z ^= z >> 1; z ^= z >> 2; z ^= z >> 4; z ^= z >> 8; return z & (DIM - 1);
}
// Swizzle sigma2 (HW-validated R6/R7). GF(2)-linear.
constexpr int swz_c(int s) {
  int m = s ^ ((s >> 6) & 63);
  return m ^ ((m >> 3) & 7);
}
__device__ __forceinline__ int sfun(int z) {
  z ^= z >> 1; z ^= z >> 2; z ^= z >> 4; z ^= z >> 8; return z & (DIM - 1);
}
__device__ __forceinline__ int swz(int s) {
  int m = s ^ ((s >> 6) & 63);
  return m ^ ((m >> 3) & 7);
}

// Compile-time XOR-offset tables (sigma2 and sfun are linear over GF(2)):
// addr(t,j) = base(t) ^ K[j].
struct KT { int A[16], B[16], C[16], G[16]; };
constexpr KT mkKT() {
  KT k{};
  for (int j = 0; j < 16; ++j) {
    k.A[j] = swz_c(j << 8);           // pass A: j = z{8-11}
    k.B[j] = swz_c(j << 4);           // pass B: j = z{4-7}
    k.C[j] = swz_c(j);                // pass C: j = z{0-3} (also encode)
    k.G[j] = swz_c(sfun_c(j << 8));   // CNOT-perm gather composed with A
  }
  return k;
}
constexpr KT KTab = mkKT();

__device__ __forceinline__ v2 block_reduce_sum2(v2 v, v2* red) {
  const int tid = threadIdx.x;
#pragma unroll
  for (int off = 32; off > 0; off >>= 1) {
    v.x += __shfl_down(v.x, off, 64);
    v.y += __shfl_down(v.y, off, 64);
  }
  if ((tid & 63) == 0) red[tid >> 6] = v;
  __syncthreads();
  if (tid == 0) {
    v2 s = sp(0.f);
#pragma unroll
    for (int i = 0; i < NT / 64; ++i) s += red[i];
    red[0] = s;
  }
  __syncthreads();
  v2 r = red[0];
  __syncthreads();
  return r;
}

// Packed complex pair update, two rows at once (v_pk_fma_f32 material).
__device__ __forceinline__ void apply_pair(v2& r0, v2& i0, v2& r1, v2& i1,
    const float2 u00, const float2 u01, const float2 u10, const float2 u11) {
  v2 nr0 = pkfma(i1, -u01.y, pkfma(r1, u01.x, pkfma(i0, -u00.y, r0 * sp(u00.x))));
  v2 ni0 = pkfma(r1,  u01.y, pkfma(i1, u01.x, pkfma(r0,  u00.y, i0 * sp(u00.x))));
  v2 nr1 = pkfma(i1, -u11.y, pkfma(r1, u11.x, pkfma(i0, -u10.y, r0 * sp(u10.x))));
  v2 ni1 = pkfma(r1,  u11.y, pkfma(i1, u11.x, pkfma(r0,  u10.y, i0 * sp(u10.x))));
  r0 = nr0; i0 = ni0; r1 = nr1; i1 = ni1;
}

// 4 gates; reg slot-bit i holds z-bit (zbase+i) -> qubit QTOP-i (QTOP=11-zbase).
template <int QTOP>
__device__ __forceinline__ void gates4(v2 re[16], v2 im[16], const float2* GL) {
#pragma unroll
  for (int i = 0; i < 4; ++i) {
    const int q = QTOP - i;
    const float2 u00 = GL[q * 4 + 0], u01 = GL[q * 4 + 1];
    const float2 u10 = GL[q * 4 + 2], u11 = GL[q * 4 + 3];
#pragma unroll
    for (int pe = 0; pe < 8; ++pe) {
      const int e0 = ((pe >> i) << (i + 1)) | (pe & ((1 << i) - 1));
      const int e1 = e0 | (1 << i);
      apply_pair(re[e0], im[e0], re[e1], im[e1], u00, u01, u10, u11);
    }
  }
}

#define LOAD16(BASE, KARR)                        \
  _Pragma("unroll")                               \
  for (int j = 0; j < 16; ++j) {                  \
    const float4 v = st[(BASE) ^ KTab.KARR[j]];   \
    re[j] = mkv2(v.x, v.y);                       \
    im[j] = mkv2(v.z, v.w);                       \
  }
#define STORE16(BASE, KARR)                       \
  _Pragma("unroll")                               \
  for (int j = 0; j < 16; ++j)                    \
    st[(BASE) ^ KTab.KARR[j]] =                   \
        make_float4(re[j].x, re[j].y, im[j].x, im[j].y);

__global__ __launch_bounds__(NT, 2) void qsim_kernel(
    const float* __restrict__ x, const float* __restrict__ w,
    float* __restrict__ out) {
  extern __shared__ __align__(16) char smem[];
  float4* st   = (float4*)smem;                  // 64 KB: unit=(re0,re1,im0,im1)
  float2* gmat = (float2*)(st + DIM);            // 1.5 KB
  v2*     red  = (v2*)(gmat + NLAYER * NQ * 4);  // 32 B

  const int t = threadIdx.x;
  const int lane6 = t & 63, w2 = t >> 6;
  const long r0 = 2L * blockIdx.x;

  // --- gate matrices (48 gates, one thread each) ---
  if (t < NLAYER * NQ) {
    const float* wp = w + t * 3;
    float phi = wp[0], th = wp[1], om = wp[2];
    float sn, cc, sa, ca, sb, cb;
    sincosf(0.5f * th, &sn, &cc);
    sincosf(0.5f * (phi + om), &sa, &ca);
    sincosf(0.5f * (phi - om), &sb, &cb);
    float2* g = &gmat[t * 4];
    g[0] = make_float2(ca * cc, -sa * cc);   // U00
    g[1] = make_float2(-cb * sn, -sb * sn);  // U01
    g[2] = make_float2(cb * sn, -sb * sn);   // U10
    g[3] = make_float2(ca * cc, sa * cc);    // U11
  }

  // --- load 16 consecutive x from each of 2 rows, norms ---
  const float4* xa = (const float4*)(x + r0 * DIM) + t * 4;
  const float4* xb = (const float4*)(x + (r0 + 1) * DIM) + t * 4;
  float va[16], vb[16];
#pragma unroll
  for (int k = 0; k < 4; ++k) {
    const float4 A = xa[k], Bv = xb[k];
    va[k * 4 + 0] = A.x;  va[k * 4 + 1] = A.y;
    va[k * 4 + 2] = A.z;  va[k * 4 + 3] = A.w;
    vb[k * 4 + 0] = Bv.x; vb[k * 4 + 1] = Bv.y;
    vb[k * 4 + 2] = Bv.z; vb[k * 4 + 3] = Bv.w;
  }
  v2 ss = sp(0.f);
#pragma unroll
  for (int e = 0; e < 16; ++e) { ss.x += va[e] * va[e]; ss.y += vb[e] * vb[e]; }
  const v2 nsq = block_reduce_sum2(ss, red);   // barriers also cover gmat init
  const float n0 = sqrtf(nsq.x), n1 = sqrtf(nsq.y);
  const bool ok0 = n0 > 1e-10f, ok1 = n1 > 1e-10f;
  const float i0f = ok0 ? 1.0f / n0 : 0.f, i1f = ok1 ? 1.0f / n1 : 0.f;

  // --- pattern bases (all accesses are base ^ compile-time K) ---
  const int baseA = swz(t);                                    // z = t | j<<8
  const int baseB = swz((t & 15) | (w2 << 8) | (((t >> 4) & 3) << 10));
  const int baseC = swz((lane6 << 4) | (w2 << 10));            // z = j | l<<4 | w<<10
  const int gbase = swz(sfun(t));

  // encode (pattern C): logical z = t*16 + e at st[baseC ^ KC[e]]
#pragma unroll
  for (int e = 0; e < 16; ++e)
    st[baseC ^ KTab.C[e]] = make_float4(ok0 ? va[e] * i0f : 0.015625f,
                                        ok1 ? vb[e] * i1f : 0.015625f, 0.f, 0.f);
  __syncthreads();

  v2 re[16], im[16];
#pragma unroll
  for (int L = 0; L < NLAYER; ++L) {
    const float2* GL = &gmat[L * NQ * 4];

    // Pass A: z-bits 8-11 (qubits 3,2,1,0). L>=1 fuses prev layer's CNOT perm.
    if (L == 0) {
      LOAD16(baseA, A)
      gates4<3>(re, im, GL);
      STORE16(baseA, A)        // in-place, no mid barrier
    } else {
      LOAD16(gbase, G)
      gates4<3>(re, im, GL);
      __syncthreads();         // all gathers consumed before scatter-back
      STORE16(baseA, A)
    }
    __syncthreads();

    // Pass B: z-bits 4-7 (qubits 7,6,5,4) — in-place
    LOAD16(baseB, B)
    gates4<7>(re, im, GL);
    STORE16(baseB, B)
    __syncthreads();

    // Pass C: z-bits 0-3 (qubits 11,10,9,8) — in-place
    LOAD16(baseC, C)
    gates4<11>(re, im, GL);
    STORE16(baseC, C)
    __syncthreads();
  }

  // --- output: final perm fused into gather; probs + renormalize, 2 rows ---
  float q0[16], q1[16];
  v2 ps = sp(0.f);
#pragma unroll
  for (int k = 0; k < 16; ++k) {
    const float4 v = st[gbase ^ KTab.G[k]];
    q0[k] = v.x * v.x + v.z * v.z;
    q1[k] = v.y * v.y + v.w * v.w;
    ps.x += q0[k]; ps.y += q1[k];
  }
  const v2 tot = block_reduce_sum2(ps, red);
  const bool k0 = tot.x > 1e-10f, k1 = tot.y > 1e-10f;
  const float t0 = k0 ? 1.0f / tot.x : 0.f, t1 = k1 ? 1.0f / tot.y : 0.f;
  float* o0 = out + r0 * DIM;
  float* o1 = out + (r0 + 1) * DIM;
#pragma unroll
  for (int k = 0; k < 16; ++k) {
    o0[t + k * NT] = k0 ? q0[k] * t0 : (1.0f / DIM);
    o1[t + k * NT] = k1 ? q1[k] * t1 : (1.0f / DIM);
  }
}

extern "C" void kernel_launch(void* const* d_in, const int* in_sizes, int n_in,
                              void* d_out, int out_size, void* d_ws, size_t ws_size,
                              hipStream_t stream) {
  const float* x = (const float*)d_in[0];
  const float* w = (const float*)d_in[1];
  float* out = (float*)d_out;
  const int B = in_sizes[0] / DIM;
  const size_t smem = DIM * sizeof(float4) + NLAYER * NQ * 4 * sizeof(float2)
                    + (NT / 64) * sizeof(v2);
  qsim_kernel<<<B / 2, NT, smem, stream>>>(x, w, out);
}